// Round 9
// baseline (21317.712 us; speedup 1.0000x reference)
//
#include <hip/hip_runtime.h>
#include <hip/hip_bf16.h>

// BiLSTM-CRF fused pipeline for MI355X (gfx950) — round 8.
// DTYPE RESOLUTION (r6 vs r7 differential): float inputs are FLOAT32 (per the reference),
// output is FLOAT32. r7's NaN came from reading f32 weights as bf16 pairs -> garbage
// -> inf*0 in MFMA. This round: all float inputs read as const float*; W_hh / fc_w are
// converted once per launch to bf16 device-global copies (LSTM inner loop unchanged);
// GEMM stages convert f32->bf16 while staging to LDS. Scratch in static device globals
// (~104 MiB bss, ws_size==0 on this harness). No runtime allocation APIs anywhere.
//
// Flow: cvt(whh0,whh1,fcw) -> repack -> [8 chunks: GEMM(l0) -> LSTM(l0 -> h0)] -> init_em
//       -> [8 chunks: GEMM(l1) -> LSTM(l1, fused FC -> em)] -> CRF -> reduce.
// Scalar f32 output = sum_b (logZ_b - gold_b).

typedef __attribute__((ext_vector_type(8))) short bf16x8;
typedef __attribute__((ext_vector_type(4))) float f32x4;
typedef __attribute__((ext_vector_type(2))) float f32x2;

#define B_ 128
#define T_ 512
#define H_ 256
#define TC 64          // chunk timesteps
#define NC 8           // chunks

// ---------------- static device scratch (~104 MiB zero-init bss) ----------------
__device__ __align__(256) unsigned short g_h0[(size_t)T_*B_*512];        // 67,108,864 B
__device__ __align__(256) unsigned short g_xgc[(size_t)B_*2*TC*1024];    // 33,554,432 B
__device__ __align__(256) float          g_em[(size_t)T_*B_*20];         //  5,242,880 B
__device__ __align__(256) unsigned short g_whhb0[2*1024*256];            //  1,048,576 B
__device__ __align__(256) unsigned short g_whhb1[2*1024*256];            //  1,048,576 B
__device__ __align__(256) unsigned short g_fcwb[20*512];                 //     20,480 B
__device__ __align__(256) uint4          g_ws0[12288];                   //    196,608 B
__device__ __align__(256) uint4          g_ws1[12288];                   //    196,608 B
__device__ __align__(256) float          g_state[256*512];               //    524,288 B
__device__ __align__(256) float          g_perb[128];

__device__ __forceinline__ unsigned short f2bf(float f){
  unsigned u = __float_as_uint(f);
  return (unsigned short)((u + 0x7FFFu + ((u>>16)&1u)) >> 16);   // RNE
}
__device__ __forceinline__ f32x2 bfpair(unsigned u){
  f32x2 r; r.x = __uint_as_float(u<<16); r.y = __uint_as_float(u & 0xFFFF0000u); return r;
}
__device__ __forceinline__ float sigm(float x){ return 1.0f/(1.0f + __expf(-x)); }
__device__ __forceinline__ float tanh_f(float x){ return 1.0f - 2.0f/(1.0f + __expf(2.0f*x)); }
__device__ __forceinline__ float cl(float x, float b){ return fminf(b, fmaxf(-b, x)); }  // also scrubs NaN

// ---------------- f32 -> bf16 bulk convert (4 elements/thread) ----------------
__global__ __launch_bounds__(256) void k_cvt(const float* __restrict__ src,
    unsigned short* __restrict__ dst, int n4)
{
  int i = blockIdx.x*256 + threadIdx.x;
  if (i >= n4) return;
  float4 v = ((const float4*)src)[i];
  unsigned lo = (unsigned)f2bf(v.x) | ((unsigned)f2bf(v.y) << 16);
  unsigned hi = (unsigned)f2bf(v.z) | ((unsigned)f2bf(v.w) << 16);
  ((uint2*)dst)[i] = make_uint2(lo, hi);
}

// ---------------- repack streamed W_hh tail (k 208..255) into [dir][j 0..5][row] x 16B
__global__ __launch_bounds__(256) void k_repack(const unsigned short* __restrict__ whhb, int which)
{
  int idx = blockIdx.x*256 + threadIdx.x;           // 2*6*1024 = 12288
  if (idx >= 12288) return;
  int dir = idx / 6144, rem = idx - dir*6144, j = rem >> 10, row = rem & 1023;
  const uint4* src = (const uint4*)(whhb + ((size_t)dir*1024 + row)*H_ + 208 + j*8);
  (which ? g_ws1 : g_ws0)[idx] = *src;
}

// ---------------- em init: g_em[t*128+b][c] = fc_b[c]  (f32)
__global__ __launch_bounds__(256) void k_init_em(const float* __restrict__ fcb)
{
  int idx = blockIdx.x*256 + threadIdx.x;           // 65536*20
  if (idx >= T_*B_*20) return;
  g_em[idx] = fcb[idx % 20];
}

// ---------------- MFMA GEMM chunk: g_xgc[b][dir][pl][n'] = A[m][k] @ W[n][k]^T + (b_ih+b_hh)[n]
// mode 0: A row = emb[ids[b][t_abs]] (f32, K=300 ragged). mode 1: A = g_h0 (bf16, K=512).
__global__ __launch_bounds__(256) void k_gemm_chunk(
    const int* __restrict__ ids, const float* __restrict__ embf,
    const float* __restrict__ W,
    const float* __restrict__ bih, const float* __restrict__ bhh,
    int KA, int K, int chunk, int mode)
{
  int pl = blockIdx.x;                 // 0..TC-1
  int n0 = blockIdx.y * 128;           // 0..2047
  int dirB = n0 >> 10;                 // block-uniform direction
  int p = chunk*TC + pl;
  int t_abs = dirB ? (T_-1-p) : p;
  __shared__ __align__(16) unsigned short Al[128][40];   // 80B row stride (2-way bank = free)
  __shared__ __align__(16) unsigned short Bl[128][40];
  int tid = threadIdx.x;
  int wave = tid >> 6, lane = tid & 63;
  int wm = wave >> 1, wn = wave & 1;
  int col = lane & 15, quad = lane >> 4;
  f32x4 acc[4][4];
  #pragma unroll
  for (int i=0;i<4;i++)
    #pragma unroll
    for (int j=0;j<4;j++) acc[i][j] = (f32x4){0.f,0.f,0.f,0.f};
  int Kc = (K + 31) >> 5;
  int r = tid >> 2, co = (tid & 3) * 8;
  const unsigned short* Arow0 = g_h0 + (size_t)t_abs*128*KA;
  int id0 = 0, id1 = 0;
  if (mode == 0){ id0 = ids[r*T_ + t_abs]; id1 = ids[(64+r)*T_ + t_abs]; }
  for (int kc=0; kc<Kc; kc++){
    int k0 = kc*32;
    if (mode == 0){                    // A-tile from f32 embedding rows, cvt to bf16
      if (k0 + 32 <= K){
        const float* e0 = embf + (size_t)id0*300 + k0 + co;
        const float* e1 = embf + (size_t)id1*300 + k0 + co;
        float4 a0v = *(const float4*)e0,     a1v = *(const float4*)(e0+4);
        float4 b0v = *(const float4*)e1,     b1v = *(const float4*)(e1+4);
        *(uint2*)(&Al[r][co])      = make_uint2((unsigned)f2bf(a0v.x)|((unsigned)f2bf(a0v.y)<<16),
                                                (unsigned)f2bf(a0v.z)|((unsigned)f2bf(a0v.w)<<16));
        *(uint2*)(&Al[r][co+4])    = make_uint2((unsigned)f2bf(a1v.x)|((unsigned)f2bf(a1v.y)<<16),
                                                (unsigned)f2bf(a1v.z)|((unsigned)f2bf(a1v.w)<<16));
        *(uint2*)(&Al[64+r][co])   = make_uint2((unsigned)f2bf(b0v.x)|((unsigned)f2bf(b0v.y)<<16),
                                                (unsigned)f2bf(b0v.z)|((unsigned)f2bf(b0v.w)<<16));
        *(uint2*)(&Al[64+r][co+4]) = make_uint2((unsigned)f2bf(b1v.x)|((unsigned)f2bf(b1v.y)<<16),
                                                (unsigned)f2bf(b1v.z)|((unsigned)f2bf(b1v.w)<<16));
      } else {                         // ragged tail k0=288: guard, zero-fill
        #pragma unroll
        for (int e=0;e<8;e++){
          int k = k0 + co + e;
          Al[r][co+e]    = (k < K) ? f2bf(embf[(size_t)id0*300 + k]) : (unsigned short)0;
          Al[64+r][co+e] = (k < K) ? f2bf(embf[(size_t)id1*300 + k]) : (unsigned short)0;
        }
      }
    } else {                           // A-tile from g_h0 (bf16, 16B aligned, K=512)
      #pragma unroll
      for (int it=0; it<2; it++){
        int rr = it*64 + r;
        uint4 v = *(const uint4*)(Arow0 + (size_t)rr*KA + k0 + co);
        *(uint4*)(&Al[rr][co]) = v;
      }
    }
    if (k0 + 32 <= K){                 // B-tile: W f32 rows n0..n0+127, cvt to bf16
      #pragma unroll
      for (int it=0; it<2; it++){
        int rr = it*64 + r;
        const float* wp = W + (size_t)(n0+rr)*K + k0 + co;
        float4 w0 = *(const float4*)wp, w1 = *(const float4*)(wp+4);
        *(uint2*)(&Bl[rr][co])   = make_uint2((unsigned)f2bf(w0.x)|((unsigned)f2bf(w0.y)<<16),
                                              (unsigned)f2bf(w0.z)|((unsigned)f2bf(w0.w)<<16));
        *(uint2*)(&Bl[rr][co+4]) = make_uint2((unsigned)f2bf(w1.x)|((unsigned)f2bf(w1.y)<<16),
                                              (unsigned)f2bf(w1.z)|((unsigned)f2bf(w1.w)<<16));
      }
    } else {                           // ragged tail: per-element guard, zero-fill
      #pragma unroll
      for (int it=0; it<2; it++){
        int rr = it*64 + r;
        const float* wp = W + (size_t)(n0+rr)*K;
        #pragma unroll
        for (int e=0;e<8;e++){
          int k = k0 + co + e;
          Bl[rr][co+e] = (k < K) ? f2bf(wp[k]) : (unsigned short)0;
        }
      }
    }
    __syncthreads();
    bf16x8 af[4], bfv[4];
    #pragma unroll
    for (int mi=0;mi<4;mi++) af[mi]  = *(const bf16x8*)(&Al[wm*64 + mi*16 + col][quad*8]);
    #pragma unroll
    for (int ni=0;ni<4;ni++) bfv[ni] = *(const bf16x8*)(&Bl[wn*64 + ni*16 + col][quad*8]);
    #pragma unroll
    for (int mi=0;mi<4;mi++)
      #pragma unroll
      for (int ni=0;ni<4;ni++)
        acc[mi][ni] = __builtin_amdgcn_mfma_f32_16x16x32_bf16(af[mi], bfv[ni], acc[mi][ni], 0, 0, 0);
    __syncthreads();
  }
  // epilogue: C/D layout col=lane&15 (n), row=quad*4+reg (m=b)
  #pragma unroll
  for (int mi=0;mi<4;mi++){
    int b0 = wm*64 + mi*16 + quad*4;
    #pragma unroll
    for (int ni=0;ni<4;ni++){
      int n_ = n0 + wn*64 + ni*16 + col;
      float bias = bih[n_] + bhh[n_];
      int dir = n_ >> 10, np = n_ & 1023;
      #pragma unroll
      for (int rg=0; rg<4; rg++){
        float v = acc[mi][ni][rg] + bias;
        size_t o = (((size_t)(b0+rg)*2 + dir)*TC + pl)*1024 + np;
        g_xgc[o] = f2bf(v);
      }
    }
  }
}

// ---------------- LSTM recurrence chunk: grid 256 = (b,dir); 1024 threads.
// mode 0: writes g_h0.  mode 1: fused FC -> atomicAdd g_em (waves 6..10).
__global__ __launch_bounds__(1024) void k_lstm_chunk(
    const unsigned short* __restrict__ whhb, int chunk, int first, int mode)
{
  int b = blockIdx.x >> 1, dir = blockIdx.x & 1;
  int tid = threadIdx.x;
  __shared__ __align__(16) float hsh[256];
  __shared__ float gsh[1024];
  __shared__ uint2 wl[6][1024];                       // 48KB: k 184..207
  __shared__ unsigned fwl[320*8];                     // 10KB: fc_w slice (mode 1)
  const unsigned short* row = whhb + ((size_t)(dir*1024 + tid))*H_;
  uint4 wv[23];                                       // 92 VGPRs: k 0..183
  #pragma unroll
  for (int q=0;q<23;q++) wv[q] = ((const uint4*)row)[q];
  {
    uint4 t0 = ((const uint4*)row)[23];
    uint4 t1 = ((const uint4*)row)[24];
    uint4 t2 = ((const uint4*)row)[25];
    wl[0][tid] = make_uint2(t0.x, t0.y);
    wl[1][tid] = make_uint2(t0.z, t0.w);
    wl[2][tid] = make_uint2(t1.x, t1.y);
    wl[3][tid] = make_uint2(t1.z, t1.w);
    wl[4][tid] = make_uint2(t2.x, t2.y);
    wl[5][tid] = make_uint2(t2.z, t2.w);
  }
  int fcact = (mode == 1) && (tid >= 384) && (tid < 704);
  int fc_tid = tid - 384;                             // 0..319: c = fc_tid>>4, p = fc_tid&15
  if (fcact){
    int c = fc_tid >> 4, p_ = fc_tid & 15;
    const uint4* src = (const uint4*)(g_fcwb + (size_t)c*512 + dir*256 + p_*16);
    uint4 w0 = src[0], w1 = src[1];
    *(uint4*)(&fwl[fc_tid*8])     = w0;
    *(uint4*)(&fwl[fc_tid*8 + 4]) = w1;
  }
  float* st = g_state + (size_t)blockIdx.x*512;
  float cst = 0.f;
  if (tid < 256){
    hsh[tid] = first ? 0.f : st[tid];
    cst      = first ? 0.f : st[256+tid];
  }
  const uint4* wsb = (mode ? g_ws1 : g_ws0) + (size_t)dir*6*1024;
  const unsigned short* xrow = g_xgc + (((size_t)b*2 + dir)*TC)*1024;
  __syncthreads();
  int p0 = chunk*TC;
  unsigned short xcur = xrow[tid];
  for (int s=0; s<TC; s++){
    unsigned short xnxt = (s < TC-1) ? xrow[(size_t)(s+1)*1024 + tid] : (unsigned short)0;
    const f32x4* hp4 = (const f32x4*)hsh;
    f32x2 a0 = {0.f,0.f}, a1 = {0.f,0.f};
    #pragma unroll
    for (int q=0;q<23;q++){                           // VGPR weights, h broadcast from LDS
      f32x4 ha = hp4[2*q], hb = hp4[2*q+1];
      a0 += bfpair(wv[q].x) * __builtin_shufflevector(ha, ha, 0, 1);
      a1 += bfpair(wv[q].y) * __builtin_shufflevector(ha, ha, 2, 3);
      a0 += bfpair(wv[q].z) * __builtin_shufflevector(hb, hb, 0, 1);
      a1 += bfpair(wv[q].w) * __builtin_shufflevector(hb, hb, 2, 3);
    }
    #pragma unroll
    for (int j=0;j<6;j++){                            // LDS weights
      uint2 w2 = wl[j][tid];
      f32x4 ha = hp4[46+j];
      a0 += bfpair(w2.x) * __builtin_shufflevector(ha, ha, 0, 1);
      a1 += bfpair(w2.y) * __builtin_shufflevector(ha, ha, 2, 3);
    }
    #pragma unroll
    for (int j=0;j<6;j++){                            // L2-streamed packed weights
      uint4 w4 = wsb[j*1024 + tid];
      f32x4 ha = hp4[52+2*j], hb = hp4[53+2*j];
      a0 += bfpair(w4.x) * __builtin_shufflevector(ha, ha, 0, 1);
      a1 += bfpair(w4.y) * __builtin_shufflevector(ha, ha, 2, 3);
      a0 += bfpair(w4.z) * __builtin_shufflevector(hb, hb, 0, 1);
      a1 += bfpair(w4.w) * __builtin_shufflevector(hb, hb, 2, 3);
    }
    {
      f32x2 xv = bfpair((unsigned)xcur);              // xv.x = bf16 value of xcur
      gsh[tid] = a0.x + a0.y + a1.x + a1.y + xv.x;
    }
    __syncthreads();
    int p = p0 + s;
    int time = dir ? (T_-1-p) : p;
    if (tid < 256){                                   // gates i,f,g,o over row blocks of 256
      float gi = cl(gsh[tid],30.f), gf = cl(gsh[256+tid],30.f);
      float gg = cl(gsh[512+tid],30.f), go = cl(gsh[768+tid],30.f);
      cst = sigm(gf)*cst + sigm(gi)*tanh_f(gg);
      cst = cl(cst, 512.f);
      float h = sigm(go)*tanh_f(cl(cst,30.f));
      hsh[tid] = h;
      if (mode == 0)
        g_h0[((size_t)time*B_ + b)*512 + (size_t)dir*H_ + tid] = f2bf(h);
    }
    __syncthreads();
    if (fcact){                                       // partial FC: g_em[t][b][c] += h . fcw[c][dir half]
      int c = fc_tid >> 4, p_ = fc_tid & 15;
      const f32x4* hp = (const f32x4*)hsh;
      const unsigned* wq = &fwl[fc_tid*8];
      f32x2 acc2 = {0.f,0.f};
      #pragma unroll
      for (int q=0;q<4;q++){
        f32x4 hv = hp[p_*4 + q];
        acc2 += bfpair(wq[2*q])   * __builtin_shufflevector(hv, hv, 0, 1);
        acc2 += bfpair(wq[2*q+1]) * __builtin_shufflevector(hv, hv, 2, 3);
      }
      float part = acc2.x + acc2.y;
      part += __shfl_xor(part, 1);
      part += __shfl_xor(part, 2);
      part += __shfl_xor(part, 4);
      part += __shfl_xor(part, 8);
      if (p_ == 0) atomicAdd(&g_em[((size_t)time*B_ + b)*20 + c], part);
    }
    xcur = xnxt;
  }
  if (tid < 256){ st[tid] = hsh[tid]; st[256+tid] = cst; }
}

// ---------------- CRF NLL per batch element: g_perb[b] = logZ - gold  (one wave per b)
__global__ __launch_bounds__(64) void k_crf(
    const int* __restrict__ labels, const float* __restrict__ trans,
    const float* __restrict__ st, const float* __restrict__ en)
{
  int b = blockIdx.x, lane = threadIdx.x;
  float tcol[20];
  #pragma unroll
  for (int c=0;c<20;c++) tcol[c] = (lane<20) ? trans[c*20 + lane] : 0.f;
  float gs = 0.f;
  for (int t=lane; t<T_; t+=64){
    int tg = labels[b*T_ + t];
    gs += g_em[((size_t)t*B_ + b)*20 + tg];
    if (t < T_-1){
      int tg2 = labels[b*T_ + t + 1];
      gs += trans[tg*20 + tg2];
    }
  }
  #pragma unroll
  for (int o=32;o;o>>=1) gs += __shfl_xor(gs, o);
  float alpha = (lane<20) ? st[lane] + g_em[(size_t)b*20 + lane] : -1e30f;
  for (int t=1;t<T_;t++){
    float av[20]; float mx = -1e30f;
    #pragma unroll
    for (int c=0;c<20;c++){
      float a = __shfl(alpha, c);
      av[c] = a + tcol[c];
      mx = fmaxf(mx, av[c]);
    }
    float sm = 0.f;
    #pragma unroll
    for (int c=0;c<20;c++) sm += __expf(av[c]-mx);
    float e = (lane<20) ? g_em[((size_t)t*B_ + b)*20 + lane] : 0.f;
    alpha = (lane<20) ? (mx + __logf(sm) + e) : -1e30f;
  }
  float v = (lane<20) ? alpha + en[lane] : -1e30f;
  float mx = v;
  #pragma unroll
  for (int o=32;o;o>>=1) mx = fmaxf(mx, __shfl_xor(mx, o));
  float sm = (lane<20) ? __expf(v-mx) : 0.f;
  #pragma unroll
  for (int o=32;o;o>>=1) sm += __shfl_xor(sm, o);
  float logZ = mx + __logf(sm);
  if (lane == 0){
    int tg0 = labels[b*T_], tgL = labels[b*T_ + T_-1];
    float num = gs + st[tg0] + en[tgL];
    g_perb[b] = logZ - num;
  }
}

// f32 scalar out; NaN/inf backstop sentinel 5e8 for decodability.
__global__ __launch_bounds__(64) void k_reduce(float* __restrict__ out){
  int lane = threadIdx.x;
  float v = g_perb[lane] + g_perb[lane + 64];
  #pragma unroll
  for (int o=32;o;o>>=1) v += __shfl_xor(v, o);
  if (lane == 0){
    unsigned u = __float_as_uint(v);
    if ((u & 0x7F800000u) == 0x7F800000u) v = 5.0e8f;   // NaN or inf -> sentinel
    out[0] = v;
  }
}

extern "C" void kernel_launch(void* const* d_in, const int* in_sizes, int n_in,
                              void* d_out, int out_size, void* d_ws, size_t ws_size,
                              hipStream_t stream)
{
  const int*   ids    = (const int*)d_in[0];
  const int*   labels = (const int*)d_in[1];
  const float* emb    = (const float*)d_in[2];
  const float* wih0   = (const float*)d_in[3];
  const float* whh0   = (const float*)d_in[4];
  const float* bih0   = (const float*)d_in[5];
  const float* bhh0   = (const float*)d_in[6];
  const float* wih1   = (const float*)d_in[7];
  const float* whh1   = (const float*)d_in[8];
  const float* bih1   = (const float*)d_in[9];
  const float* bhh1   = (const float*)d_in[10];
  const float* fcw    = (const float*)d_in[11];
  const float* fcb    = (const float*)d_in[12];
  const float* trans  = (const float*)d_in[13];
  const float* stt    = (const float*)d_in[14];
  const float* ent    = (const float*)d_in[15];

  unsigned short* whhb0 = nullptr; unsigned short* whhb1 = nullptr; unsigned short* fcwb = nullptr;
  hipGetSymbolAddress((void**)&whhb0, HIP_SYMBOL(g_whhb0));
  hipGetSymbolAddress((void**)&whhb1, HIP_SYMBOL(g_whhb1));
  hipGetSymbolAddress((void**)&fcwb,  HIP_SYMBOL(g_fcwb));

  k_cvt<<<512, 256, 0, stream>>>(whh0, whhb0, 131072);   // 2*1024*256/4
  k_cvt<<<512, 256, 0, stream>>>(whh1, whhb1, 131072);
  k_cvt<<<10,  256, 0, stream>>>(fcw,  fcwb,  2560);     // 20*512/4
  k_repack<<<48, 256, 0, stream>>>(whhb0, 0);
  k_repack<<<48, 256, 0, stream>>>(whhb1, 1);

  for (int c=0; c<NC; c++){
    k_gemm_chunk<<<dim3(TC,16), 256, 0, stream>>>(ids, emb, wih0, bih0, bhh0, 320, 300, c, 0);
    k_lstm_chunk<<<256, 1024, 0, stream>>>(whhb0, c, c==0, 0);
  }
  k_init_em<<<5120, 256, 0, stream>>>(fcb);
  for (int c=0; c<NC; c++){
    k_gemm_chunk<<<dim3(TC,16), 256, 0, stream>>>(ids, emb, wih1, bih1, bhh1, 512, 512, c, 1);
    k_lstm_chunk<<<256, 1024, 0, stream>>>(whhb1, c, c==0, 1);
  }

  k_crf   <<<128, 64, 0, stream>>>(labels, trans, stt, ent);
  k_reduce<<<1, 64, 0, stream>>>((float*)d_out);
}